// Round 15
// baseline (181.128 us; speedup 1.0000x reference)
//
#include <hip/hip_runtime.h>

// GRUObservationCellLogvar — R15: R14 + half-chunk copy staging (40KB LDS buf,
// wave-private rows) => LDS ~74KB => 2 resident blocks/CU (needs VGPR<=128).
// Pipeline per tile: [store prev-half1 | issue half0] M bar [store half0 |
// issue half1] C(t+1) bar ... half-flights cover M and C windows respectively.
// N=500000, N_OBS=200000, D=32, H=128, P=4
// out = [ h_updated (500000*128) | losses (200000*32) ] fp32

typedef __attribute__((ext_vector_type(8))) short bf16x8;
typedef __attribute__((ext_vector_type(4))) float f32x4;

__device__ inline unsigned short f2bf_rne(float x) {
    union { float f; unsigned int u; } v; v.f = x;
    unsigned int r = (v.u + 0x7fffu + ((v.u >> 16) & 1u)) >> 16;
    return (unsigned short)r;
}
__device__ inline unsigned short f2bf_tr(float x) {
    return (unsigned short)(__float_as_uint(x) >> 16);
}
__device__ inline float bf2f(unsigned short u) {
    return __uint_as_float(((unsigned int)u) << 16);
}
__device__ inline float fast_sigmoid(float x) {
    return __builtin_amdgcn_rcpf(1.f + __expf(-x));
}
__device__ inline float fast_tanh(float x) {
    const float a = fabsf(x);
    const float t = __expf(-2.f * a);
    const float r = (1.f - t) * __builtin_amdgcn_rcpf(1.f + t);
    return __builtin_copysignf(r, x);
}
// async 16B/lane global -> LDS (wave-uniform LDS base + lane*16; per-lane global addr)
__device__ inline void gl_lds16(const float* g, float* lds_base) {
    __builtin_amdgcn_global_load_lds(
        (const __attribute__((address_space(1))) void*)g,
        (__attribute__((address_space(3))) void*)lds_base, 16, 0, 0);
}

// ---- B prepack: 98304 bf16 = 8 cg * 24 frags * 64 lanes * 8 (RNE) ----
__global__ __launch_bounds__(256) void k_prepack(const float* __restrict__ W_ih,
                                                 const float* __restrict__ W_hh,
                                                 unsigned short* __restrict__ B) {
    const int i = blockIdx.x * 256 + threadIdx.x;
    const int w    = i / 12288;
    const int rem  = i - w * 12288;
    const int f    = rem >> 9;
    const int rem2 = rem & 511;
    const int l    = rem2 >> 3;
    const int j    = rem2 & 7;
    const int c    = w * 16 + (l & 15);
    const int ko   = (l >> 4) * 8 + j;
    float val;
    if (f < 8) {
        const int k = f * 32 + ko;
        val = (k < 128) ? W_ih[c * 128 + k] : W_hh[c * 128 + (k - 128)];
    } else if (f < 16) {
        const int k = (f - 8) * 32 + ko;
        val = (k < 128) ? W_ih[(128 + c) * 128 + k] : W_hh[(128 + c) * 128 + (k - 128)];
    } else if (f < 20) {
        const int k = (f - 16) * 32 + ko;
        val = W_ih[(256 + c) * 128 + k];
    } else {
        const int k = (f - 20 + 4) * 32 + ko;
        val = W_hh[(256 + c) * 128 + (k - 128)];
    }
    B[i] = f2bf_rne(val);
}

__global__ __launch_bounds__(256) void k_flag(const int* __restrict__ i_obs,
                                              unsigned char* __restrict__ flags, int n) {
    const int i = blockIdx.x * 256 + threadIdx.x;
    if (i < n) flags[i_obs[i]] = 1;
}

__global__ __launch_bounds__(256) void k_copy(const f32x4* __restrict__ src,
                                              f32x4* __restrict__ dst, long n4) {
    long i = (long)blockIdx.x * blockDim.x + threadIdx.x;
    long stride = (long)gridDim.x * blockDim.x;
    for (; i < n4; i += stride) dst[i] = src[i];
}

struct PrefRegs {
    float mean[4], lv[4], X[4], M[4];
    f32x4 hv[4];
    int idx[4];
};

__global__ __launch_bounds__(512) void k_pers(
    const float* __restrict__ h, const float* __restrict__ p,
    const float* __restrict__ X_obs, const float* __restrict__ M_obs,
    const int* __restrict__ i_obs,
    const float* __restrict__ w_prep, const float* __restrict__ bias_prep,
    const unsigned short* __restrict__ Bpk,
    const float* __restrict__ b_ih, const float* __restrict__ b_hh,
    float* __restrict__ out_h, float* __restrict__ out_losses,
    const unsigned char* __restrict__ flags,
    int NT, int chunk, int Nh, int do_copy)
{
    __shared__ unsigned short sA[4 * 8 * 64 * 8];   // 32 KB
    __shared__ float buf[80 * 128];                 // 40 KB half-chunk staging
    __shared__ int sIdx[64];

    const int tid  = threadIdx.x;
    const int d    = tid & 31;
    const int wid  = tid >> 6;
    const int lane = tid & 63;
    const int cw   = wid * 16 + (lane & 15);

    // ---- resident constants ----
    float wp[16], bp[4];
    #pragma unroll
    for (int t = 0; t < 16; ++t) wp[t] = w_prep[d * 16 + t];
    #pragma unroll
    for (int t = 0; t < 4; ++t) bp[t] = bias_prep[d * 4 + t];

    bf16x8 breg[24];
    {
        const bf16x8* bsrc = reinterpret_cast<const bf16x8*>(Bpk) + wid * 1536;
        #pragma unroll
        for (int f = 0; f < 24; ++f) breg[f] = bsrc[f * 64 + lane];
    }
    const float bR  = b_ih[cw]       + b_hh[cw];
    const float bZ  = b_ih[128 + cw] + b_hh[128 + cw];
    const float bIN = b_ih[256 + cw];
    const float bHN = b_hh[256 + cw];

    const int ksA  = d >> 3;                 // gi frag coords
    const int l16  = ((d >> 1) & 3) * 16;
    const int j0   = (d & 1) * 4;
    const int ksE  = 4 + (cw >> 5);          // epilogue h_old coords
    const int l16E = ((cw >> 3) & 3) * 16;
    const int jE   = cw & 7;

    const bf16x8* aptr = reinterpret_cast<const bf16x8*>(sA);

    PrefRegs R;

    auto G_load = [&](int t) {
        const int row0 = t * 64;
        #pragma unroll
        for (int ps = 0; ps < 4; ++ps) {
            const int r   = ps * 16 + (tid >> 5);
            const int idx = i_obs[row0 + r];
            R.idx[ps]  = idx;
            R.mean[ps] = p[(size_t)idx * 64 + d];
            R.lv[ps]   = p[(size_t)idx * 64 + 32 + d];
            R.X[ps]    = X_obs[(size_t)(row0 + r) * 32 + d];
            R.M[ps]    = M_obs[(size_t)(row0 + r) * 32 + d];
            R.hv[ps]   = *reinterpret_cast<const f32x4*>(h + (size_t)idx * 128 + d * 4);
        }
    };

    // issue 40KB half-chunk (80 rows) async global->LDS; wave w owns rows [w*10,w*10+10)
    auto COPY_issue_half = [&](int t, int half) {
        const long rlo = (long)t * chunk + half * 80;
        const float* hs = h + rlo * 128;
        const int rbase = wid * 10;
        #pragma unroll
        for (int q = 0; q < 5; ++q) {                // 2 rows (1KB) per instr
            const int row = rbase + q * 2;
            gl_lds16(hs + (size_t)row * 128 + lane * 4, &buf[row * 128]);
        }
    };

    // store the same wave-private rows: LDS -> flag-gated nt stores.
    // per-wave program order (ds_read before any later gl_lds re-issue) => race-free.
    auto COPY_store_half = [&](int t, int half) {
        const long rlo = (long)t * chunk + half * 80;
        f32x4* hd = reinterpret_cast<f32x4*>(out_h + rlo * 128);
        const unsigned char* fl = flags + rlo;
        const f32x4* b4 = reinterpret_cast<const f32x4*>(buf);
        const int rbase = wid * 10;
        #pragma unroll
        for (int q = 0; q < 5; ++q) {
            const int row = rbase + q * 2 + (lane >> 5);
            const int c4  = lane & 31;
            const f32x4 v = b4[row * 32 + c4];
            if (!fl[row]) __builtin_nontemporal_store(v, &hd[row * 32 + c4]);
        }
    };

    auto C_phase = [&](int t) {
        const int row0 = t * 64;
        #pragma unroll
        for (int ps = 0; ps < 4; ++ps) {
            const int r  = ps * 16 + (tid >> 5);
            const int mt = r >> 4;
            if (d == 0) sIdx[r] = R.idx[ps];
            const float lv      = fminf(fmaxf(R.lv[ps], -10.f), 10.f);
            const float inv_sig = __expf(-0.5f * lv);
            const float X = R.X[ps], Mv = R.M[ps], mean = R.mean[ps];
            const float err = fminf(fmaxf((X - mean) * inv_sig, -1e6f), 1e6f);
            out_losses[(size_t)(row0 + r) * 32 + d] =
                0.5f * ((err * err + lv + 1.8378770664093453f) * Mv);
            ushort4 u;
            float g0 = fmaf(X, wp[0], fmaf(mean, wp[4], fmaf(lv, wp[8],  fmaf(err, wp[12], bp[0]))));
            float g1 = fmaf(X, wp[1], fmaf(mean, wp[5], fmaf(lv, wp[9],  fmaf(err, wp[13], bp[1]))));
            float g2 = fmaf(X, wp[2], fmaf(mean, wp[6], fmaf(lv, wp[10], fmaf(err, wp[14], bp[2]))));
            float g3 = fmaf(X, wp[3], fmaf(mean, wp[7], fmaf(lv, wp[11], fmaf(err, wp[15], bp[3]))));
            u.x = f2bf_tr(fmaxf(g0, 0.f) * Mv);
            u.y = f2bf_tr(fmaxf(g1, 0.f) * Mv);
            u.z = f2bf_tr(fmaxf(g2, 0.f) * Mv);
            u.w = f2bf_tr(fmaxf(g3, 0.f) * Mv);
            *reinterpret_cast<ushort4*>(&sA[((mt * 8 + ksA) * 64 + (r & 15) + l16) * 8 + j0]) = u;
            const f32x4 v = R.hv[ps];
            ushort4 uh;
            uh.x = f2bf_tr(v.x); uh.y = f2bf_tr(v.y); uh.z = f2bf_tr(v.z); uh.w = f2bf_tr(v.w);
            *reinterpret_cast<ushort4*>(&sA[((mt * 8 + ksA + 4) * 64 + (r & 15) + l16) * 8 + j0]) = uh;
        }
    };

    auto M_phase = [&]() {
        #pragma unroll
        for (int mt = 0; mt < 4; ++mt) {
            f32x4 accR = {0.f, 0.f, 0.f, 0.f};
            f32x4 accZ = {0.f, 0.f, 0.f, 0.f};
            f32x4 accIN = {0.f, 0.f, 0.f, 0.f};
            f32x4 accHN = {0.f, 0.f, 0.f, 0.f};
            #pragma unroll
            for (int ks = 0; ks < 8; ++ks) {
                const bf16x8 af = aptr[(mt * 8 + ks) * 64 + lane];
                accR = __builtin_amdgcn_mfma_f32_16x16x32_bf16(af, breg[ks],     accR, 0, 0, 0);
                accZ = __builtin_amdgcn_mfma_f32_16x16x32_bf16(af, breg[8 + ks], accZ, 0, 0, 0);
                if (ks < 4) accIN = __builtin_amdgcn_mfma_f32_16x16x32_bf16(af, breg[16 + ks], accIN, 0, 0, 0);
                else        accHN = __builtin_amdgcn_mfma_f32_16x16x32_bf16(af, breg[16 + ks], accHN, 0, 0, 0);
            }
            const int r15b = (lane >> 4) * 4;
            #pragma unroll
            for (int reg = 0; reg < 4; ++reg) {
                const int r15 = r15b + reg;
                const int idx = sIdx[mt * 16 + r15];
                const float hp = bf2f(sA[((mt * 8 + ksE) * 64 + r15 + l16E) * 8 + jE]);
                const float xr  = accR[reg]  + bR;
                const float xz  = accZ[reg]  + bZ;
                const float xin = accIN[reg] + bIN;
                const float xhn = accHN[reg] + bHN;
                const float rg = fast_sigmoid(xr);
                const float zg = fast_sigmoid(xz);
                const float ng = fast_tanh(fmaf(rg, xhn, xin));
                out_h[(size_t)idx * 128 + cw] = fmaf(zg, hp - ng, ng);
            }
        }
    };

    // ---------- persistent pipelined loop (2 barriers/tile) ----------
    int t = blockIdx.x;
    if (t >= NT) return;
    const int stride = gridDim.x;

    G_load(t);
    C_phase(t);
    __syncthreads();

    int tprev = -1;

    for (;;) {
        const int tn = t + stride;
        const bool has_next = (tn < NT);
        if (has_next) G_load(tn);            // next-tile gathers in flight
        if (do_copy) {
            if (tprev >= 0) COPY_store_half(tprev, 1);   // landed by last barrier
            COPY_issue_half(t, 0);           // 40KB in flight under M
        }
        M_phase();
        __syncthreads();                     // half0 landed; sA reads done
        if (do_copy) {
            COPY_store_half(t, 0);
            COPY_issue_half(t, 1);           // 40KB in flight under C
        }
        if (has_next) C_phase(tn);
        __syncthreads();                     // half1 landed; sA(tn) ready
        if (!has_next) {
            if (do_copy) COPY_store_half(t, 1);
            break;
        }
        tprev = t;
        t = tn;
    }
}

extern "C" void kernel_launch(void* const* d_in, const int* in_sizes, int n_in,
                              void* d_out, int out_size, void* d_ws, size_t ws_size,
                              hipStream_t stream) {
    const float* h         = (const float*)d_in[0];
    const float* p         = (const float*)d_in[1];
    const float* X_obs     = (const float*)d_in[2];
    const float* M_obs     = (const float*)d_in[3];
    const int*   i_obs     = (const int*)d_in[4];
    const float* w_prep    = (const float*)d_in[5];
    const float* bias_prep = (const float*)d_in[6];
    const float* W_ih      = (const float*)d_in[7];
    const float* W_hh      = (const float*)d_in[8];
    const float* b_ih      = (const float*)d_in[9];
    const float* b_hh      = (const float*)d_in[10];

    const int Nh   = in_sizes[0] / 128;   // 500000
    const int NOBS = in_sizes[4];         // 200000
    const int NT   = NOBS / 64;           // 3125 tiles
    const long n4  = (long)Nh * 128 / 4;

    float* out_h      = (float*)d_out;
    float* out_losses = out_h + (size_t)Nh * 128;

    unsigned short* Bpk   = (unsigned short*)d_ws;               // 192 KB
    unsigned char*  flags = (unsigned char*)d_ws + (256 << 10);  // Nh bytes
    const size_t ws_needed = (256 << 10) + (size_t)Nh;

    hipLaunchKernelGGL(k_prepack, dim3(98304 / 256), dim3(256), 0, stream,
                       W_ih, W_hh, Bpk);

    const int chunk = (NT > 0) ? Nh / NT : 0;    // 160 exact for these sizes
    const int GRID  = 512;

    if (ws_size >= ws_needed && chunk == 160 && chunk * NT == Nh && NT * 64 == NOBS) {
        (void)hipMemsetAsync(flags, 0, (size_t)Nh, stream);
        hipLaunchKernelGGL(k_flag, dim3((NOBS + 255) / 256), dim3(256), 0, stream,
                           i_obs, flags, NOBS);
        hipLaunchKernelGGL(k_pers, dim3(GRID), dim3(512), 0, stream,
                           h, p, X_obs, M_obs, i_obs, w_prep, bias_prep, Bpk,
                           b_ih, b_hh, out_h, out_losses, flags, NT, chunk, Nh, 1);
    } else {
        hipLaunchKernelGGL(k_copy, dim3(4096), dim3(256), 0, stream,
                           (const f32x4*)h, (f32x4*)out_h, n4);
        hipLaunchKernelGGL(k_pers, dim3(GRID), dim3(512), 0, stream,
                           h, p, X_obs, M_obs, i_obs, w_prep, bias_prep, Bpk,
                           b_ih, b_hh, out_h, out_losses,
                           (const unsigned char*)nullptr, NT, chunk, Nh, 0);
    }
}

// Round 16
// 172.182 us; speedup vs baseline: 1.0520x; 1.0520x over previous
//
#include <hip/hip_runtime.h>

// GRUObservationCellLogvar — R16: champion restore (= R14, best measured 173.5 µs).
// Persistent pipeline + async-LDS copy staging: copy loads issued BEFORE M_phase
// via global_load_lds (zero VGPR) so G-gathers (64KB) + copy (80KB) are in flight
// together under the MFMA window; stores drain from LDS after the barrier.
// N=500000, N_OBS=200000, D=32, H=128, P=4
// out = [ h_updated (500000*128) | losses (200000*32) ] fp32

typedef __attribute__((ext_vector_type(8))) short bf16x8;
typedef __attribute__((ext_vector_type(4))) float f32x4;

__device__ inline unsigned short f2bf_rne(float x) {
    union { float f; unsigned int u; } v; v.f = x;
    unsigned int r = (v.u + 0x7fffu + ((v.u >> 16) & 1u)) >> 16;
    return (unsigned short)r;
}
__device__ inline unsigned short f2bf_tr(float x) {
    return (unsigned short)(__float_as_uint(x) >> 16);
}
__device__ inline float bf2f(unsigned short u) {
    return __uint_as_float(((unsigned int)u) << 16);
}
__device__ inline float fast_sigmoid(float x) {
    return __builtin_amdgcn_rcpf(1.f + __expf(-x));
}
__device__ inline float fast_tanh(float x) {
    const float a = fabsf(x);
    const float t = __expf(-2.f * a);
    const float r = (1.f - t) * __builtin_amdgcn_rcpf(1.f + t);
    return __builtin_copysignf(r, x);
}
// async 16B/lane global -> LDS (wave-uniform LDS base + lane*16; per-lane global addr)
__device__ inline void gl_lds16(const float* g, float* lds_base) {
    __builtin_amdgcn_global_load_lds(
        (const __attribute__((address_space(1))) void*)g,
        (__attribute__((address_space(3))) void*)lds_base, 16, 0, 0);
}

// ---- B prepack: 98304 bf16 = 8 cg * 24 frags * 64 lanes * 8 (RNE) ----
__global__ __launch_bounds__(256) void k_prepack(const float* __restrict__ W_ih,
                                                 const float* __restrict__ W_hh,
                                                 unsigned short* __restrict__ B) {
    const int i = blockIdx.x * 256 + threadIdx.x;
    const int w    = i / 12288;
    const int rem  = i - w * 12288;
    const int f    = rem >> 9;
    const int rem2 = rem & 511;
    const int l    = rem2 >> 3;
    const int j    = rem2 & 7;
    const int c    = w * 16 + (l & 15);
    const int ko   = (l >> 4) * 8 + j;
    float val;
    if (f < 8) {
        const int k = f * 32 + ko;
        val = (k < 128) ? W_ih[c * 128 + k] : W_hh[c * 128 + (k - 128)];
    } else if (f < 16) {
        const int k = (f - 8) * 32 + ko;
        val = (k < 128) ? W_ih[(128 + c) * 128 + k] : W_hh[(128 + c) * 128 + (k - 128)];
    } else if (f < 20) {
        const int k = (f - 16) * 32 + ko;
        val = W_ih[(256 + c) * 128 + k];
    } else {
        const int k = (f - 20 + 4) * 32 + ko;
        val = W_hh[(256 + c) * 128 + (k - 128)];
    }
    B[i] = f2bf_rne(val);
}

__global__ __launch_bounds__(256) void k_flag(const int* __restrict__ i_obs,
                                              unsigned char* __restrict__ flags, int n) {
    const int i = blockIdx.x * 256 + threadIdx.x;
    if (i < n) flags[i_obs[i]] = 1;
}

__global__ __launch_bounds__(256) void k_copy(const f32x4* __restrict__ src,
                                              f32x4* __restrict__ dst, long n4) {
    long i = (long)blockIdx.x * blockDim.x + threadIdx.x;
    long stride = (long)gridDim.x * blockDim.x;
    for (; i < n4; i += stride) dst[i] = src[i];
}

struct PrefRegs {
    float mean[4], lv[4], X[4], M[4];
    f32x4 hv[4];
    int idx[4];
};

__global__ __launch_bounds__(512) void k_pers(
    const float* __restrict__ h, const float* __restrict__ p,
    const float* __restrict__ X_obs, const float* __restrict__ M_obs,
    const int* __restrict__ i_obs,
    const float* __restrict__ w_prep, const float* __restrict__ bias_prep,
    const unsigned short* __restrict__ Bpk,
    const float* __restrict__ b_ih, const float* __restrict__ b_hh,
    float* __restrict__ out_h, float* __restrict__ out_losses,
    const unsigned char* __restrict__ flags,
    int NT, int chunk, int Nh, int do_copy)
{
    __shared__ unsigned short sA[4 * 8 * 64 * 8];   // 32 KB
    __shared__ float hcopy[160 * 128];              // 80 KB copy staging
    __shared__ int sIdx[64];

    const int tid  = threadIdx.x;
    const int d    = tid & 31;
    const int wid  = tid >> 6;
    const int lane = tid & 63;
    const int cw   = wid * 16 + (lane & 15);

    // ---- resident constants ----
    float wp[16], bp[4];
    #pragma unroll
    for (int t = 0; t < 16; ++t) wp[t] = w_prep[d * 16 + t];
    #pragma unroll
    for (int t = 0; t < 4; ++t) bp[t] = bias_prep[d * 4 + t];

    bf16x8 breg[24];
    {
        const bf16x8* bsrc = reinterpret_cast<const bf16x8*>(Bpk) + wid * 1536;
        #pragma unroll
        for (int f = 0; f < 24; ++f) breg[f] = bsrc[f * 64 + lane];
    }
    const float bR  = b_ih[cw]       + b_hh[cw];
    const float bZ  = b_ih[128 + cw] + b_hh[128 + cw];
    const float bIN = b_ih[256 + cw];
    const float bHN = b_hh[256 + cw];

    const int ksA  = d >> 3;                 // gi frag coords
    const int l16  = ((d >> 1) & 3) * 16;
    const int j0   = (d & 1) * 4;
    const int ksE  = 4 + (cw >> 5);          // epilogue h_old coords
    const int l16E = ((cw >> 3) & 3) * 16;
    const int jE   = cw & 7;

    const bf16x8* aptr = reinterpret_cast<const bf16x8*>(sA);

    PrefRegs R;

    auto G_load = [&](int t) {
        const int row0 = t * 64;
        #pragma unroll
        for (int ps = 0; ps < 4; ++ps) {
            const int r   = ps * 16 + (tid >> 5);
            const int idx = i_obs[row0 + r];
            R.idx[ps]  = idx;
            R.mean[ps] = p[(size_t)idx * 64 + d];
            R.lv[ps]   = p[(size_t)idx * 64 + 32 + d];
            R.X[ps]    = X_obs[(size_t)(row0 + r) * 32 + d];
            R.M[ps]    = M_obs[(size_t)(row0 + r) * 32 + d];
            R.hv[ps]   = *reinterpret_cast<const f32x4*>(h + (size_t)idx * 128 + d * 4);
        }
    };

    // issue 80KB chunk copy as async global->LDS (no VGPR, no wait)
    auto COPY_issue = [&](int t) {
        const long rlo = (long)t * chunk;            // chunk = 160 exact
        const float* hs = h + rlo * 128;
        const int rbase = wid * 20;                  // 20 rows per wave
        #pragma unroll
        for (int q = 0; q < 10; ++q) {               // 2 rows (1KB) per instr
            const int row = rbase + q * 2;
            gl_lds16(hs + (size_t)row * 128 + lane * 4, &hcopy[row * 128]);
        }
    };

    // drain staged copy: LDS -> flag-gated nt stores
    auto COPY_store = [&](int t) {
        const long rlo = (long)t * chunk;
        f32x4* hd = reinterpret_cast<f32x4*>(out_h + rlo * 128);
        const unsigned char* fl = flags + rlo;
        const f32x4* hc = reinterpret_cast<const f32x4*>(hcopy);
        #pragma unroll
        for (int ii = 0; ii < 10; ++ii) {
            const int i5 = ii * 512 + tid;           // < 5120 always
            if (!fl[i5 >> 5]) __builtin_nontemporal_store(hc[i5], &hd[i5]);
        }
    };

    auto C_phase = [&](int t) {
        const int row0 = t * 64;
        #pragma unroll
        for (int ps = 0; ps < 4; ++ps) {
            const int r  = ps * 16 + (tid >> 5);
            const int mt = r >> 4;
            if (d == 0) sIdx[r] = R.idx[ps];
            const float lv      = fminf(fmaxf(R.lv[ps], -10.f), 10.f);
            const float inv_sig = __expf(-0.5f * lv);
            const float X = R.X[ps], Mv = R.M[ps], mean = R.mean[ps];
            const float err = fminf(fmaxf((X - mean) * inv_sig, -1e6f), 1e6f);
            out_losses[(size_t)(row0 + r) * 32 + d] =
                0.5f * ((err * err + lv + 1.8378770664093453f) * Mv);
            ushort4 u;
            float g0 = fmaf(X, wp[0], fmaf(mean, wp[4], fmaf(lv, wp[8],  fmaf(err, wp[12], bp[0]))));
            float g1 = fmaf(X, wp[1], fmaf(mean, wp[5], fmaf(lv, wp[9],  fmaf(err, wp[13], bp[1]))));
            float g2 = fmaf(X, wp[2], fmaf(mean, wp[6], fmaf(lv, wp[10], fmaf(err, wp[14], bp[2]))));
            float g3 = fmaf(X, wp[3], fmaf(mean, wp[7], fmaf(lv, wp[11], fmaf(err, wp[15], bp[3]))));
            u.x = f2bf_tr(fmaxf(g0, 0.f) * Mv);
            u.y = f2bf_tr(fmaxf(g1, 0.f) * Mv);
            u.z = f2bf_tr(fmaxf(g2, 0.f) * Mv);
            u.w = f2bf_tr(fmaxf(g3, 0.f) * Mv);
            *reinterpret_cast<ushort4*>(&sA[((mt * 8 + ksA) * 64 + (r & 15) + l16) * 8 + j0]) = u;
            const f32x4 v = R.hv[ps];
            ushort4 uh;
            uh.x = f2bf_tr(v.x); uh.y = f2bf_tr(v.y); uh.z = f2bf_tr(v.z); uh.w = f2bf_tr(v.w);
            *reinterpret_cast<ushort4*>(&sA[((mt * 8 + ksA + 4) * 64 + (r & 15) + l16) * 8 + j0]) = uh;
        }
    };

    auto M_phase = [&]() {
        #pragma unroll
        for (int mt = 0; mt < 4; ++mt) {
            f32x4 accR = {0.f, 0.f, 0.f, 0.f};
            f32x4 accZ = {0.f, 0.f, 0.f, 0.f};
            f32x4 accIN = {0.f, 0.f, 0.f, 0.f};
            f32x4 accHN = {0.f, 0.f, 0.f, 0.f};
            #pragma unroll
            for (int ks = 0; ks < 8; ++ks) {
                const bf16x8 af = aptr[(mt * 8 + ks) * 64 + lane];
                accR = __builtin_amdgcn_mfma_f32_16x16x32_bf16(af, breg[ks],     accR, 0, 0, 0);
                accZ = __builtin_amdgcn_mfma_f32_16x16x32_bf16(af, breg[8 + ks], accZ, 0, 0, 0);
                if (ks < 4) accIN = __builtin_amdgcn_mfma_f32_16x16x32_bf16(af, breg[16 + ks], accIN, 0, 0, 0);
                else        accHN = __builtin_amdgcn_mfma_f32_16x16x32_bf16(af, breg[16 + ks], accHN, 0, 0, 0);
            }
            const int r15b = (lane >> 4) * 4;
            #pragma unroll
            for (int reg = 0; reg < 4; ++reg) {
                const int r15 = r15b + reg;
                const int idx = sIdx[mt * 16 + r15];
                const float hp = bf2f(sA[((mt * 8 + ksE) * 64 + r15 + l16E) * 8 + jE]);
                const float xr  = accR[reg]  + bR;
                const float xz  = accZ[reg]  + bZ;
                const float xin = accIN[reg] + bIN;
                const float xhn = accHN[reg] + bHN;
                const float rg = fast_sigmoid(xr);
                const float zg = fast_sigmoid(xz);
                const float ng = fast_tanh(fmaf(rg, xhn, xin));
                out_h[(size_t)idx * 128 + cw] = fmaf(zg, hp - ng, ng);
            }
        }
    };

    // ---------- persistent pipelined loop (2 barriers/tile) ----------
    int t = blockIdx.x;
    if (t >= NT) return;
    const int stride = gridDim.x;

    G_load(t);
    C_phase(t);
    __syncthreads();

    for (;;) {
        const int tn = t + stride;
        const bool has_next = (tn < NT);
        if (has_next) G_load(tn);       // next-tile gathers in flight
        if (do_copy) COPY_issue(t);     // +80KB async in flight under M
        M_phase();
        __syncthreads();                // drains vmcnt: hcopy landed; M LDS reads done
        if (do_copy) COPY_store(t);     // LDS -> gated nt stores
        if (!has_next) break;
        C_phase(tn);                    // pack regs -> sA for next tile
        __syncthreads();
        t = tn;
    }
}

extern "C" void kernel_launch(void* const* d_in, const int* in_sizes, int n_in,
                              void* d_out, int out_size, void* d_ws, size_t ws_size,
                              hipStream_t stream) {
    const float* h         = (const float*)d_in[0];
    const float* p         = (const float*)d_in[1];
    const float* X_obs     = (const float*)d_in[2];
    const float* M_obs     = (const float*)d_in[3];
    const int*   i_obs     = (const int*)d_in[4];
    const float* w_prep    = (const float*)d_in[5];
    const float* bias_prep = (const float*)d_in[6];
    const float* W_ih      = (const float*)d_in[7];
    const float* W_hh      = (const float*)d_in[8];
    const float* b_ih      = (const float*)d_in[9];
    const float* b_hh      = (const float*)d_in[10];

    const int Nh   = in_sizes[0] / 128;   // 500000
    const int NOBS = in_sizes[4];         // 200000
    const int NT   = NOBS / 64;           // 3125 tiles
    const long n4  = (long)Nh * 128 / 4;

    float* out_h      = (float*)d_out;
    float* out_losses = out_h + (size_t)Nh * 128;

    unsigned short* Bpk   = (unsigned short*)d_ws;               // 192 KB
    unsigned char*  flags = (unsigned char*)d_ws + (256 << 10);  // Nh bytes
    const size_t ws_needed = (256 << 10) + (size_t)Nh;

    hipLaunchKernelGGL(k_prepack, dim3(98304 / 256), dim3(256), 0, stream,
                       W_ih, W_hh, Bpk);

    const int chunk = (NT > 0) ? Nh / NT : 0;    // 160 exact for these sizes
    const int GRID  = 512;

    if (ws_size >= ws_needed && chunk == 160 && chunk * NT == Nh && NT * 64 == NOBS) {
        (void)hipMemsetAsync(flags, 0, (size_t)Nh, stream);
        hipLaunchKernelGGL(k_flag, dim3((NOBS + 255) / 256), dim3(256), 0, stream,
                           i_obs, flags, NOBS);
        hipLaunchKernelGGL(k_pers, dim3(GRID), dim3(512), 0, stream,
                           h, p, X_obs, M_obs, i_obs, w_prep, bias_prep, Bpk,
                           b_ih, b_hh, out_h, out_losses, flags, NT, chunk, Nh, 1);
    } else {
        hipLaunchKernelGGL(k_copy, dim3(4096), dim3(256), 0, stream,
                           (const f32x4*)h, (f32x4*)out_h, n4);
        hipLaunchKernelGGL(k_pers, dim3(GRID), dim3(512), 0, stream,
                           h, p, X_obs, M_obs, i_obs, w_prep, bias_prep, Bpk,
                           b_ih, b_hh, out_h, out_losses,
                           (const unsigned char*)nullptr, NT, chunk, Nh, 0);
    }
}

// Round 17
// 171.284 us; speedup vs baseline: 1.0575x; 1.0052x over previous
//
#include <hip/hip_runtime.h>

// GRUObservationCellLogvar — R17: R16 champion + relaxed barriers.
// bar1: s_waitcnt vmcnt(16) lgkmcnt(0) + s_barrier  (epilogue stores ride)
// bar2: s_waitcnt lgkmcnt(0) + s_barrier            (all stores ride into next M)
// Everything else identical to R16 (173.5/172.2 µs).
// N=500000, N_OBS=200000, D=32, H=128, P=4
// out = [ h_updated (500000*128) | losses (200000*32) ] fp32

typedef __attribute__((ext_vector_type(8))) short bf16x8;
typedef __attribute__((ext_vector_type(4))) float f32x4;

__device__ inline unsigned short f2bf_rne(float x) {
    union { float f; unsigned int u; } v; v.f = x;
    unsigned int r = (v.u + 0x7fffu + ((v.u >> 16) & 1u)) >> 16;
    return (unsigned short)r;
}
__device__ inline unsigned short f2bf_tr(float x) {
    return (unsigned short)(__float_as_uint(x) >> 16);
}
__device__ inline float bf2f(unsigned short u) {
    return __uint_as_float(((unsigned int)u) << 16);
}
__device__ inline float fast_sigmoid(float x) {
    return __builtin_amdgcn_rcpf(1.f + __expf(-x));
}
__device__ inline float fast_tanh(float x) {
    const float a = fabsf(x);
    const float t = __expf(-2.f * a);
    const float r = (1.f - t) * __builtin_amdgcn_rcpf(1.f + t);
    return __builtin_copysignf(r, x);
}
// async 16B/lane global -> LDS (wave-uniform LDS base + lane*16; per-lane global addr)
__device__ inline void gl_lds16(const float* g, float* lds_base) {
    __builtin_amdgcn_global_load_lds(
        (const __attribute__((address_space(1))) void*)g,
        (__attribute__((address_space(3))) void*)lds_base, 16, 0, 0);
}

// ---- B prepack: 98304 bf16 = 8 cg * 24 frags * 64 lanes * 8 (RNE) ----
__global__ __launch_bounds__(256) void k_prepack(const float* __restrict__ W_ih,
                                                 const float* __restrict__ W_hh,
                                                 unsigned short* __restrict__ B) {
    const int i = blockIdx.x * 256 + threadIdx.x;
    const int w    = i / 12288;
    const int rem  = i - w * 12288;
    const int f    = rem >> 9;
    const int rem2 = rem & 511;
    const int l    = rem2 >> 3;
    const int j    = rem2 & 7;
    const int c    = w * 16 + (l & 15);
    const int ko   = (l >> 4) * 8 + j;
    float val;
    if (f < 8) {
        const int k = f * 32 + ko;
        val = (k < 128) ? W_ih[c * 128 + k] : W_hh[c * 128 + (k - 128)];
    } else if (f < 16) {
        const int k = (f - 8) * 32 + ko;
        val = (k < 128) ? W_ih[(128 + c) * 128 + k] : W_hh[(128 + c) * 128 + (k - 128)];
    } else if (f < 20) {
        const int k = (f - 16) * 32 + ko;
        val = W_ih[(256 + c) * 128 + k];
    } else {
        const int k = (f - 20 + 4) * 32 + ko;
        val = W_hh[(256 + c) * 128 + (k - 128)];
    }
    B[i] = f2bf_rne(val);
}

__global__ __launch_bounds__(256) void k_flag(const int* __restrict__ i_obs,
                                              unsigned char* __restrict__ flags, int n) {
    const int i = blockIdx.x * 256 + threadIdx.x;
    if (i < n) flags[i_obs[i]] = 1;
}

__global__ __launch_bounds__(256) void k_copy(const f32x4* __restrict__ src,
                                              f32x4* __restrict__ dst, long n4) {
    long i = (long)blockIdx.x * blockDim.x + threadIdx.x;
    long stride = (long)gridDim.x * blockDim.x;
    for (; i < n4; i += stride) dst[i] = src[i];
}

struct PrefRegs {
    float mean[4], lv[4], X[4], M[4];
    f32x4 hv[4];
    int idx[4];
};

__global__ __launch_bounds__(512) void k_pers(
    const float* __restrict__ h, const float* __restrict__ p,
    const float* __restrict__ X_obs, const float* __restrict__ M_obs,
    const int* __restrict__ i_obs,
    const float* __restrict__ w_prep, const float* __restrict__ bias_prep,
    const unsigned short* __restrict__ Bpk,
    const float* __restrict__ b_ih, const float* __restrict__ b_hh,
    float* __restrict__ out_h, float* __restrict__ out_losses,
    const unsigned char* __restrict__ flags,
    int NT, int chunk, int Nh, int do_copy)
{
    __shared__ unsigned short sA[4 * 8 * 64 * 8];   // 32 KB
    __shared__ float hcopy[160 * 128];              // 80 KB copy staging
    __shared__ int sIdx[64];

    const int tid  = threadIdx.x;
    const int d    = tid & 31;
    const int wid  = tid >> 6;
    const int lane = tid & 63;
    const int cw   = wid * 16 + (lane & 15);

    // ---- resident constants ----
    float wp[16], bp[4];
    #pragma unroll
    for (int t = 0; t < 16; ++t) wp[t] = w_prep[d * 16 + t];
    #pragma unroll
    for (int t = 0; t < 4; ++t) bp[t] = bias_prep[d * 4 + t];

    bf16x8 breg[24];
    {
        const bf16x8* bsrc = reinterpret_cast<const bf16x8*>(Bpk) + wid * 1536;
        #pragma unroll
        for (int f = 0; f < 24; ++f) breg[f] = bsrc[f * 64 + lane];
    }
    const float bR  = b_ih[cw]       + b_hh[cw];
    const float bZ  = b_ih[128 + cw] + b_hh[128 + cw];
    const float bIN = b_ih[256 + cw];
    const float bHN = b_hh[256 + cw];

    const int ksA  = d >> 3;                 // gi frag coords
    const int l16  = ((d >> 1) & 3) * 16;
    const int j0   = (d & 1) * 4;
    const int ksE  = 4 + (cw >> 5);          // epilogue h_old coords
    const int l16E = ((cw >> 3) & 3) * 16;
    const int jE   = cw & 7;

    const bf16x8* aptr = reinterpret_cast<const bf16x8*>(sA);

    PrefRegs R;

    auto G_load = [&](int t) {
        const int row0 = t * 64;
        #pragma unroll
        for (int ps = 0; ps < 4; ++ps) {
            const int r   = ps * 16 + (tid >> 5);
            const int idx = i_obs[row0 + r];
            R.idx[ps]  = idx;
            R.mean[ps] = p[(size_t)idx * 64 + d];
            R.lv[ps]   = p[(size_t)idx * 64 + 32 + d];
            R.X[ps]    = X_obs[(size_t)(row0 + r) * 32 + d];
            R.M[ps]    = M_obs[(size_t)(row0 + r) * 32 + d];
            R.hv[ps]   = *reinterpret_cast<const f32x4*>(h + (size_t)idx * 128 + d * 4);
        }
    };

    // issue 80KB chunk copy as async global->LDS (no VGPR, no wait)
    auto COPY_issue = [&](int t) {
        const long rlo = (long)t * chunk;            // chunk = 160 exact
        const float* hs = h + rlo * 128;
        const int rbase = wid * 20;                  // 20 rows per wave
        #pragma unroll
        for (int q = 0; q < 10; ++q) {               // 2 rows (1KB) per instr
            const int row = rbase + q * 2;
            gl_lds16(hs + (size_t)row * 128 + lane * 4, &hcopy[row * 128]);
        }
    };

    // drain staged copy: LDS -> flag-gated nt stores
    auto COPY_store = [&](int t) {
        const long rlo = (long)t * chunk;
        f32x4* hd = reinterpret_cast<f32x4*>(out_h + rlo * 128);
        const unsigned char* fl = flags + rlo;
        const f32x4* hc = reinterpret_cast<const f32x4*>(hcopy);
        #pragma unroll
        for (int ii = 0; ii < 10; ++ii) {
            const int i5 = ii * 512 + tid;           // < 5120 always
            if (!fl[i5 >> 5]) __builtin_nontemporal_store(hc[i5], &hd[i5]);
        }
    };

    auto C_phase = [&](int t) {
        const int row0 = t * 64;
        #pragma unroll
        for (int ps = 0; ps < 4; ++ps) {
            const int r  = ps * 16 + (tid >> 5);
            const int mt = r >> 4;
            if (d == 0) sIdx[r] = R.idx[ps];
            const float lv      = fminf(fmaxf(R.lv[ps], -10.f), 10.f);
            const float inv_sig = __expf(-0.5f * lv);
            const float X = R.X[ps], Mv = R.M[ps], mean = R.mean[ps];
            const float err = fminf(fmaxf((X - mean) * inv_sig, -1e6f), 1e6f);
            out_losses[(size_t)(row0 + r) * 32 + d] =
                0.5f * ((err * err + lv + 1.8378770664093453f) * Mv);
            ushort4 u;
            float g0 = fmaf(X, wp[0], fmaf(mean, wp[4], fmaf(lv, wp[8],  fmaf(err, wp[12], bp[0]))));
            float g1 = fmaf(X, wp[1], fmaf(mean, wp[5], fmaf(lv, wp[9],  fmaf(err, wp[13], bp[1]))));
            float g2 = fmaf(X, wp[2], fmaf(mean, wp[6], fmaf(lv, wp[10], fmaf(err, wp[14], bp[2]))));
            float g3 = fmaf(X, wp[3], fmaf(mean, wp[7], fmaf(lv, wp[11], fmaf(err, wp[15], bp[3]))));
            u.x = f2bf_tr(fmaxf(g0, 0.f) * Mv);
            u.y = f2bf_tr(fmaxf(g1, 0.f) * Mv);
            u.z = f2bf_tr(fmaxf(g2, 0.f) * Mv);
            u.w = f2bf_tr(fmaxf(g3, 0.f) * Mv);
            *reinterpret_cast<ushort4*>(&sA[((mt * 8 + ksA) * 64 + (r & 15) + l16) * 8 + j0]) = u;
            const f32x4 v = R.hv[ps];
            ushort4 uh;
            uh.x = f2bf_tr(v.x); uh.y = f2bf_tr(v.y); uh.z = f2bf_tr(v.z); uh.w = f2bf_tr(v.w);
            *reinterpret_cast<ushort4*>(&sA[((mt * 8 + ksA + 4) * 64 + (r & 15) + l16) * 8 + j0]) = uh;
        }
    };

    auto M_phase = [&]() {
        #pragma unroll
        for (int mt = 0; mt < 4; ++mt) {
            f32x4 accR = {0.f, 0.f, 0.f, 0.f};
            f32x4 accZ = {0.f, 0.f, 0.f, 0.f};
            f32x4 accIN = {0.f, 0.f, 0.f, 0.f};
            f32x4 accHN = {0.f, 0.f, 0.f, 0.f};
            #pragma unroll
            for (int ks = 0; ks < 8; ++ks) {
                const bf16x8 af = aptr[(mt * 8 + ks) * 64 + lane];
                accR = __builtin_amdgcn_mfma_f32_16x16x32_bf16(af, breg[ks],     accR, 0, 0, 0);
                accZ = __builtin_amdgcn_mfma_f32_16x16x32_bf16(af, breg[8 + ks], accZ, 0, 0, 0);
                if (ks < 4) accIN = __builtin_amdgcn_mfma_f32_16x16x32_bf16(af, breg[16 + ks], accIN, 0, 0, 0);
                else        accHN = __builtin_amdgcn_mfma_f32_16x16x32_bf16(af, breg[16 + ks], accHN, 0, 0, 0);
            }
            const int r15b = (lane >> 4) * 4;
            #pragma unroll
            for (int reg = 0; reg < 4; ++reg) {
                const int r15 = r15b + reg;
                const int idx = sIdx[mt * 16 + r15];
                const float hp = bf2f(sA[((mt * 8 + ksE) * 64 + r15 + l16E) * 8 + jE]);
                const float xr  = accR[reg]  + bR;
                const float xz  = accZ[reg]  + bZ;
                const float xin = accIN[reg] + bIN;
                const float xhn = accHN[reg] + bHN;
                const float rg = fast_sigmoid(xr);
                const float zg = fast_sigmoid(xz);
                const float ng = fast_tanh(fmaf(rg, xhn, xin));
                out_h[(size_t)idx * 128 + cw] = fmaf(zg, hp - ng, ng);
            }
        }
    };

    // ---------- persistent pipelined loop (2 relaxed barriers/tile) ----------
    int t = blockIdx.x;
    if (t >= NT) return;
    const int stride = gridDim.x;

    G_load(t);
    C_phase(t);
    __syncthreads();                    // prologue: full sync (simple, once)

    for (;;) {
        const int tn = t + stride;
        const bool has_next = (tn < NT);
        if (has_next) G_load(tn);       // next-tile gathers in flight
        if (do_copy) COPY_issue(t);     // +80KB async in flight under M
        M_phase();
        // relaxed bar1: G-loads + gl_lds drained (24+10 oldest); this tile's
        // 16 scattered epilogue stores (newest) stay in flight.
        asm volatile("s_waitcnt vmcnt(16) lgkmcnt(0)" ::: "memory");
        __builtin_amdgcn_s_barrier();
        if (do_copy) COPY_store(t);     // LDS -> gated nt stores
        if (!has_next) break;
        C_phase(tn);                    // pack regs -> sA for next tile
        // relaxed bar2: LDS visibility only; all stores ride into next M window.
        asm volatile("s_waitcnt lgkmcnt(0)" ::: "memory");
        __builtin_amdgcn_s_barrier();
        t = tn;
    }
}

extern "C" void kernel_launch(void* const* d_in, const int* in_sizes, int n_in,
                              void* d_out, int out_size, void* d_ws, size_t ws_size,
                              hipStream_t stream) {
    const float* h         = (const float*)d_in[0];
    const float* p         = (const float*)d_in[1];
    const float* X_obs     = (const float*)d_in[2];
    const float* M_obs     = (const float*)d_in[3];
    const int*   i_obs     = (const int*)d_in[4];
    const float* w_prep    = (const float*)d_in[5];
    const float* bias_prep = (const float*)d_in[6];
    const float* W_ih      = (const float*)d_in[7];
    const float* W_hh      = (const float*)d_in[8];
    const float* b_ih      = (const float*)d_in[9];
    const float* b_hh      = (const float*)d_in[10];

    const int Nh   = in_sizes[0] / 128;   // 500000
    const int NOBS = in_sizes[4];         // 200000
    const int NT   = NOBS / 64;           // 3125 tiles
    const long n4  = (long)Nh * 128 / 4;

    float* out_h      = (float*)d_out;
    float* out_losses = out_h + (size_t)Nh * 128;

    unsigned short* Bpk   = (unsigned short*)d_ws;               // 192 KB
    unsigned char*  flags = (unsigned char*)d_ws + (256 << 10);  // Nh bytes
    const size_t ws_needed = (256 << 10) + (size_t)Nh;

    hipLaunchKernelGGL(k_prepack, dim3(98304 / 256), dim3(256), 0, stream,
                       W_ih, W_hh, Bpk);

    const int chunk = (NT > 0) ? Nh / NT : 0;    // 160 exact for these sizes
    const int GRID  = 512;

    if (ws_size >= ws_needed && chunk == 160 && chunk * NT == Nh && NT * 64 == NOBS) {
        (void)hipMemsetAsync(flags, 0, (size_t)Nh, stream);
        hipLaunchKernelGGL(k_flag, dim3((NOBS + 255) / 256), dim3(256), 0, stream,
                           i_obs, flags, NOBS);
        hipLaunchKernelGGL(k_pers, dim3(GRID), dim3(512), 0, stream,
                           h, p, X_obs, M_obs, i_obs, w_prep, bias_prep, Bpk,
                           b_ih, b_hh, out_h, out_losses, flags, NT, chunk, Nh, 1);
    } else {
        hipLaunchKernelGGL(k_copy, dim3(4096), dim3(256), 0, stream,
                           (const f32x4*)h, (f32x4*)out_h, n4);
        hipLaunchKernelGGL(k_pers, dim3(GRID), dim3(512), 0, stream,
                           h, p, X_obs, M_obs, i_obs, w_prep, bias_prep, Bpk,
                           b_ih, b_hh, out_h, out_losses,
                           (const unsigned char*)nullptr, NT, chunk, Nh, 0);
    }
}